// Round 1
// 324.856 us; speedup vs baseline: 1.0787x; 1.0787x over previous
//
#include <hip/hip_runtime.h>
#include <hip/hip_bf16.h>
#include <math.h>

// Problem constants: B=4, T=4096, C=1024, H=16, D=64, BLOCK=128
//   M = B*T = 16384 rows
//   GEMM1: [16384,1024] @ [1024,3072] -> qkv
//   attn : 2048 blocks of (128x64) q,k,v, causal-within-block softmax
//   GEMM2: [16384,1024] @ [1024,1024] + bias -> out (fp32)

typedef __bf16 bf16_t;
typedef __bf16 bf16x8 __attribute__((ext_vector_type(8)));
typedef float  f32x4  __attribute__((ext_vector_type(4)));

typedef const __attribute__((address_space(1))) void* gptr_t;
typedef __attribute__((address_space(3))) void* lptr_t;

// ---------------------------------------------------------------- cvt: f32 -> bf16
__global__ __launch_bounds__(256) void cvt_f32_bf16(const float* __restrict__ in,
                                                    bf16_t* __restrict__ out, size_t n) {
    size_t stride = (size_t)gridDim.x * blockDim.x * 4;
    for (size_t i = ((size_t)blockIdx.x * blockDim.x + threadIdx.x) * 4; i < n; i += stride) {
        float4 v = *(const float4*)(in + i);
        bf16_t t[4];
        t[0] = (bf16_t)v.x; t[1] = (bf16_t)v.y; t[2] = (bf16_t)v.z; t[3] = (bf16_t)v.w;
        *(uint2*)(out + i) = *(uint2*)t;
    }
}

// ------------------------------- transpose+cvt: W[K][N] fp32 -> Wt[N][K] bf16, LDS-tiled
__global__ __launch_bounds__(256) void transpose_cvt(const float* __restrict__ in,
                                                     bf16_t* __restrict__ out, int K, int N) {
    __shared__ float tile[32][33];
    const int tx = threadIdx.x & 31, ty = threadIdx.x >> 5;   // 32 x 8
    const int bx = blockIdx.x, by = blockIdx.y;               // N/32, K/32
    #pragma unroll
    for (int i = 0; i < 4; i++) {
        const int k = by * 32 + ty + i * 8;
        tile[ty + i * 8][tx] = in[(size_t)k * N + bx * 32 + tx];
    }
    __syncthreads();
    #pragma unroll
    for (int i = 0; i < 4; i++) {
        const int n = bx * 32 + ty + i * 8;
        out[(size_t)n * K + by * 32 + tx] = (bf16_t)tile[tx][ty + i * 8];
    }
}

// ---------------------------------------------------------------- GEMM (B-transposed)
// C[M][N] = A[M][K] * Bt[N][K]^T   (bf16 in, fp32 accum)
// 256x256 tile, BK=64, 8 waves (2Mx4N), 128 KiB double-buffered LDS.
// 8-phase-style schedule: per K-tile, 4 phases of {12 swizzled ds_read_b128;
// stage prefetch; raw s_barrier; setprio(1); 16 MFMA; setprio(0); raw s_barrier}.
// Only one vmcnt-draining barrier (__syncthreads) per K-tile, placed 2-3 MFMA
// phases after the prefetch issue so HBM latency hides under compute.
// LDS XOR-swizzle (T2): 16B-chunk col ^= (row&7), applied on the global SOURCE
// address (global_load_lds writes linearly) and identically on the ds_read addr.
template <bool BF16_OUT, bool BIAS>
__global__ __launch_bounds__(512, 2) void gemm256(const bf16_t* __restrict__ A,
                                                  const bf16_t* __restrict__ Bt,
                                                  void* __restrict__ Cout,
                                                  const float* __restrict__ bias,
                                                  int M, int N, int K) {
    __shared__ bf16_t As[2][256 * 64];   // [dbuf][row*64 + col]
    __shared__ bf16_t Bs[2][256 * 64];

    const int tid  = threadIdx.x;
    const int lane = tid & 63, wave = tid >> 6;
    const int quad = lane >> 4, l16 = lane & 15;
    const int wm = wave >> 2, wn = wave & 3;   // 2 x 4 wave grid, each owns 128x64 of C
    const int bn = blockIdx.x, bm = blockIdx.y;

    const bf16_t* Ab = A  + (size_t)bm * 256 * K;
    const bf16_t* Bb = Bt + (size_t)bn * 256 * K;

    // staging geometry: per (matrix, half h, i): thread covers chunk j = i*512+tid
    // of a 128x64 half-tile; row = h*128 + i*64 + (tid>>3); src chunk-col is
    // inverse-swizzled so a swizzled READ sees logical data.
    const int r0  = tid >> 3;                 // 0..63
    const int c8s = (tid & 7) ^ (r0 & 7);     // pre-swizzled source chunk col
    const int swz = l16 & 7;                  // read-side swizzle key (row&7 of frag rows)

    f32x4 acc[8][4];
    #pragma unroll
    for (int i = 0; i < 8; ++i)
        #pragma unroll
        for (int j = 0; j < 4; ++j) acc[i][j] = (f32x4){0.f, 0.f, 0.f, 0.f};

#define STAGE(DST, SRC, H, I, KOFF)                                                   \
    __builtin_amdgcn_global_load_lds(                                                 \
        (gptr_t)((SRC) + (size_t)((H) * 128 + (I) * 64 + r0) * K + (KOFF) + c8s * 8), \
        (lptr_t)&(DST)[(H) * 8192 + (I) * 4096 + wave * 512], 16, 0, 0)

    // prologue: stage K-tile 0 into slot 0, full drain
    STAGE(As[0], Ab, 0, 0, 0); STAGE(As[0], Ab, 0, 1, 0);
    STAGE(As[0], Ab, 1, 0, 0); STAGE(As[0], Ab, 1, 1, 0);
    STAGE(Bs[0], Bb, 0, 0, 0); STAGE(Bs[0], Bb, 0, 1, 0);
    STAGE(Bs[0], Bb, 1, 0, 0); STAGE(Bs[0], Bb, 1, 1, 0);
    __syncthreads();

    const int NT = K >> 6;
    for (int t = 0; t < NT; ++t) {
        const int cur = t & 1;
        const bool pf = (t + 1) < NT;
        const int kk = (t + 1) << 6;
        bf16_t* Asn = As[cur ^ 1];
        bf16_t* Bsn = Bs[cur ^ 1];
        const bf16_t* Asc = As[cur];
        const bf16_t* Bsc = Bs[cur];

        #pragma unroll
        for (int q = 0; q < 4; ++q) {          // C-quadrant phases
            const int mh = q >> 1, nh = q & 1;

            bf16x8 af[4][2], bf[2][2];
            #pragma unroll
            for (int mr = 0; mr < 4; ++mr) {
                const int arow = wm * 128 + (mh * 4 + mr) * 16 + l16;
                #pragma unroll
                for (int ks = 0; ks < 2; ++ks)
                    af[mr][ks] = *(const bf16x8*)&Asc[arow * 64 + ((((ks << 2) | quad) ^ swz) << 3)];
            }
            #pragma unroll
            for (int nr = 0; nr < 2; ++nr) {
                const int brow = wn * 64 + (nh * 2 + nr) * 16 + l16;
                #pragma unroll
                for (int ks = 0; ks < 2; ++ks)
                    bf[nr][ks] = *(const bf16x8*)&Bsc[brow * 64 + ((((ks << 2) | quad) ^ swz) << 3)];
            }

            if (q == 0 && pf) {   // prefetch next A tile (issued 4 phases before use)
                STAGE(Asn, Ab, 0, 0, kk); STAGE(Asn, Ab, 0, 1, kk);
                STAGE(Asn, Ab, 1, 0, kk); STAGE(Asn, Ab, 1, 1, kk);
            }
            if (q == 1 && pf) {   // prefetch next B tile
                STAGE(Bsn, Bb, 0, 0, kk); STAGE(Bsn, Bb, 0, 1, kk);
                STAGE(Bsn, Bb, 1, 0, kk); STAGE(Bsn, Bb, 1, 1, kk);
            }

            __builtin_amdgcn_s_barrier();      // raw: no implicit vmcnt drain
            __builtin_amdgcn_s_setprio(1);
            #pragma unroll
            for (int mr = 0; mr < 4; ++mr)
                #pragma unroll
                for (int nr = 0; nr < 2; ++nr)
                    #pragma unroll
                    for (int ks = 0; ks < 2; ++ks)
                        acc[mh * 4 + mr][nh * 2 + nr] = __builtin_amdgcn_mfma_f32_16x16x32_bf16(
                            af[mr][ks], bf[nr][ks], acc[mh * 4 + mr][nh * 2 + nr], 0, 0, 0);
            __builtin_amdgcn_s_setprio(0);

            if (q < 3)
                __builtin_amdgcn_s_barrier();  // raw phase separator
            else
                __syncthreads();               // K-tile boundary: drain prefetch + fence
        }
    }
#undef STAGE

    // epilogue: C/D layout col=lane&15, row=quad*4+reg
    #pragma unroll
    for (int mr = 0; mr < 8; ++mr) {
        #pragma unroll
        for (int nr = 0; nr < 4; ++nr) {
            const int gcol = bn * 256 + wn * 64 + nr * 16 + l16;
            #pragma unroll
            for (int reg = 0; reg < 4; ++reg) {
                const int grow = bm * 256 + wm * 128 + mr * 16 + quad * 4 + reg;
                float v = acc[mr][nr][reg];
                if (BIAS) v += bias[gcol];
                if (BF16_OUT)
                    ((bf16_t*)Cout)[(size_t)grow * N + gcol] = (bf16_t)v;
                else
                    ((float*)Cout)[(size_t)grow * N + gcol] = v;
            }
        }
    }
}

// ---------------------------------------------------------------- block-local attention
// One workgroup per (b, blk, h). q,k: [128][72] LDS; v stored TRANSPOSED [64][136] so
// PV B-fragments are ds_read_b128. LDS total 54272 B -> 3 blocks/CU.
__global__ __launch_bounds__(256, 3) void attn_kernel(const bf16_t* __restrict__ qkv,
                                                      bf16_t* __restrict__ attn_out) {
    __shared__ __align__(16) char smem[54272];
    bf16_t* qs = (bf16_t*)smem;                   // [128][72]
    bf16_t* ks = (bf16_t*)(smem + 18432);         // [128][72]
    bf16_t* vT = (bf16_t*)(smem + 36864);         // [64][136]  vT[c][r] = v[r][c]
    bf16_t* ps = (bf16_t*)smem;                   // [128][136] overlays qs+ks (34816 <= 36864)

    const int tid = threadIdx.x;
    const int lane = tid & 63, wave = tid >> 6;
    const int quad = lane >> 4, l16 = lane & 15;

    const int bid = blockIdx.x;
    const int h = bid & 15;
    const int blk = (bid >> 4) & 31;
    const int b = bid >> 9;
    const int row0 = (b * 32 + blk) * 128;   // row base in [16384]
    const int LDQ = 3072;

    // ---- stage q,k (vector), v transposed (scalar scatter, one-time)
    for (int t = tid; t < 128 * 8; t += 256) {
        const int r = t >> 3;
        const int c = (t & 7) * 8;           // element offset
        const bf16_t* src = qkv + (size_t)(row0 + r) * LDQ + h * 64;
        *(uint4*)&qs[r * 72 + c] = *(const uint4*)(src + c);
        *(uint4*)&ks[r * 72 + c] = *(const uint4*)(src + 1024 + c);
        bf16x8 vv = *(const bf16x8*)(src + 2048 + c);
        #pragma unroll
        for (int j = 0; j < 8; j++)
            vT[(c + j) * 136 + r] = vv[j];
    }
    __syncthreads();

    // ---- S = q k^T / 8 : wave handles rows [wave*32, wave*32+32) x 128 cols
    f32x4 sfrag[2][8];
    for (int mr = 0; mr < 2; mr++)
        for (int nc = 0; nc < 8; nc++)
            sfrag[mr][nc] = (f32x4){0.f, 0.f, 0.f, 0.f};

    #pragma unroll
    for (int ksl = 0; ksl < 2; ksl++) {     // K=64 in two slices of 32
        bf16x8 aq[2], bk[8];
        #pragma unroll
        for (int mr = 0; mr < 2; mr++)
            aq[mr] = *(const bf16x8*)&qs[(wave * 32 + mr * 16 + l16) * 72 + ksl * 32 + quad * 8];
        #pragma unroll
        for (int nc = 0; nc < 8; nc++)
            bk[nc] = *(const bf16x8*)&ks[(nc * 16 + l16) * 72 + ksl * 32 + quad * 8];
        #pragma unroll
        for (int mr = 0; mr < 2; mr++)
            #pragma unroll
            for (int nc = 0; nc < 8; nc++)
                sfrag[mr][nc] = __builtin_amdgcn_mfma_f32_16x16x32_bf16(aq[mr], bk[nc], sfrag[mr][nc], 0, 0, 0);
    }

    // ---- scale + causal mask (C-layout: row=quad*4+reg, col=nc*16+l16)
    #pragma unroll
    for (int mr = 0; mr < 2; mr++) {
        #pragma unroll
        for (int nc = 0; nc < 8; nc++) {
            #pragma unroll
            for (int reg = 0; reg < 4; reg++) {
                const int row = wave * 32 + mr * 16 + quad * 4 + reg;
                const int col = nc * 16 + l16;
                float s = sfrag[mr][nc][reg] * 0.125f;
                if (col > row) s = -INFINITY;
                sfrag[mr][nc][reg] = s;
            }
        }
    }

    // ---- softmax per row (reduce across 16 lanes of the row-group + 8 col frags)
    #pragma unroll
    for (int mr = 0; mr < 2; mr++) {
        #pragma unroll
        for (int reg = 0; reg < 4; reg++) {
            float m = -INFINITY;
            #pragma unroll
            for (int nc = 0; nc < 8; nc++) m = fmaxf(m, sfrag[mr][nc][reg]);
            #pragma unroll
            for (int off = 1; off < 16; off <<= 1) m = fmaxf(m, __shfl_xor(m, off));
            float sum = 0.f;
            #pragma unroll
            for (int nc = 0; nc < 8; nc++) {
                float e = __expf(sfrag[mr][nc][reg] - m);
                sfrag[mr][nc][reg] = e;
                sum += e;
            }
            #pragma unroll
            for (int off = 1; off < 16; off <<= 1) sum += __shfl_xor(sum, off);
            const float inv = 1.0f / (sum + 1e-6f);
            #pragma unroll
            for (int nc = 0; nc < 8; nc++) sfrag[mr][nc][reg] *= inv;
        }
    }

    __syncthreads();   // all waves done reading qs/ks before P overlays them

    // ---- write P (bf16) to LDS [128][136]
    #pragma unroll
    for (int mr = 0; mr < 2; mr++)
        #pragma unroll
        for (int nc = 0; nc < 8; nc++)
            #pragma unroll
            for (int reg = 0; reg < 4; reg++) {
                const int row = wave * 32 + mr * 16 + quad * 4 + reg;
                const int col = nc * 16 + l16;
                ps[row * 136 + col] = (bf16_t)sfrag[mr][nc][reg];
            }
    __syncthreads();

    // ---- O = P @ V : rows [wave*32, +32) x 64 cols, K=128 in 4 slices; V from vT (b128)
    f32x4 oacc[2][4];
    for (int mr = 0; mr < 2; mr++)
        for (int nd = 0; nd < 4; nd++)
            oacc[mr][nd] = (f32x4){0.f, 0.f, 0.f, 0.f};

    #pragma unroll
    for (int ksl = 0; ksl < 4; ksl++) {
        bf16x8 ap[2];
        #pragma unroll
        for (int mr = 0; mr < 2; mr++)
            ap[mr] = *(const bf16x8*)&ps[(wave * 32 + mr * 16 + l16) * 136 + ksl * 32 + quad * 8];
        #pragma unroll
        for (int nd = 0; nd < 4; nd++) {
            bf16x8 bv = *(const bf16x8*)&vT[(nd * 16 + l16) * 136 + ksl * 32 + quad * 8];
            #pragma unroll
            for (int mr = 0; mr < 2; mr++)
                oacc[mr][nd] = __builtin_amdgcn_mfma_f32_16x16x32_bf16(ap[mr], bv, oacc[mr][nd], 0, 0, 0);
        }
    }

    // ---- store O bf16 into attn buffer [16384][1024]
    #pragma unroll
    for (int mr = 0; mr < 2; mr++)
        #pragma unroll
        for (int nd = 0; nd < 4; nd++)
            #pragma unroll
            for (int reg = 0; reg < 4; reg++) {
                const int row = row0 + wave * 32 + mr * 16 + quad * 4 + reg;
                const int col = h * 64 + nd * 16 + l16;
                attn_out[(size_t)row * 1024 + col] = (bf16_t)oacc[mr][nd][reg];
            }
}

// ---------------------------------------------------------------- launch
extern "C" void kernel_launch(void* const* d_in, const int* in_sizes, int n_in,
                              void* d_out, int out_size, void* d_ws, size_t ws_size,
                              hipStream_t stream) {
    const float* x     = (const float*)d_in[0];   // [4,4096,1024]
    const float* Wqkv  = (const float*)d_in[1];   // [1024,3072]
    const float* Wproj = (const float*)d_in[2];   // [1024,1024]
    const float* bproj = (const float*)d_in[3];   // [1024]

    const int M = 16384, C = 1024, N1 = 3072;

    // workspace carve (bytes): all 16B aligned
    char* ws = (char*)d_ws;
    bf16_t* xb     = (bf16_t*)(ws);                                   // 32 MB
    bf16_t* wqkvT  = (bf16_t*)(ws + 33554432);                        //  6 MB  [3072][1024]
    bf16_t* wprojT = (bf16_t*)(ws + 39845888);                        //  2 MB  [1024][1024]
    bf16_t* qkvb   = (bf16_t*)(ws + 41943040);                        // 96 MB  [16384][3072]
    bf16_t* attnb  = (bf16_t*)(ws + 142606336);                       // 32 MB  [16384][1024]
    // total 168 MB

    cvt_f32_bf16<<<8192, 256, 0, stream>>>(x, xb, (size_t)M * C);
    transpose_cvt<<<dim3(N1 / 32, C / 32), 256, 0, stream>>>(Wqkv, wqkvT, C, N1);
    transpose_cvt<<<dim3(C / 32, C / 32), 256, 0, stream>>>(Wproj, wprojT, C, C);

    gemm256<true, false><<<dim3(N1 / 256, M / 256), 512, 0, stream>>>(
        xb, wqkvT, (void*)qkvb, nullptr, M, N1, C);

    attn_kernel<<<2048, 256, 0, stream>>>(qkvb, attnb);

    gemm256<false, true><<<dim3(C / 256, M / 256), 512, 0, stream>>>(
        attnb, wprojT, d_out, bproj, M, C, C);
}